// Round 8
// baseline (135.757 us; speedup 1.0000x reference)
//
#include <hip/hip_runtime.h>
#include <hip/hip_bf16.h>

// Problem constants
#define B_    2048
#define NC_   32
#define H1_   64
#define H2_   32
#define CLS_  10
#define M_    496
#define EPS_  1e-5f

typedef __attribute__((ext_vector_type(8))) short bf16x8;  // 8 bf16 (4 VGPRs)
typedef __attribute__((ext_vector_type(4))) float f32x4;   // MFMA C/D

union F8  { int4 i; bf16x8 h; };
union F16 { float4 v[4]; float f[16]; };

// float -> bf16 (RNE)
__device__ __forceinline__ short f2bf(float f) {
    unsigned u = __float_as_uint(f);
    u = (u + 0x7FFFu + ((u >> 16) & 1u)) >> 16;
    return (short)u;
}

// pack two floats' bf16(round-half-up) into one dword: low=e, high=o.
__device__ __forceinline__ unsigned pack_bf2(float e, float o) {
    unsigned ue = __float_as_uint(e) + 0x8000u;
    unsigned uo = __float_as_uint(o) + 0x8000u;
    return __builtin_amdgcn_perm(uo, ue, 0x07060302u);
}

// m -> (i0,i1): lexicographic pair from combinations(range(32),2).
__device__ __forceinline__ void pair_of_m(int m, int& i0, int& i1) {
    int a = 0, rem = m;
    while (rem >= (NC_ - 1 - a)) { rem -= (NC_ - 1 - a); ++a; }
    i0 = a; i1 = a + 1 + rem;
}

// ---------------- ws layout ----------------
// W2a: M_*4 frags of 64 int4 (bf16, s2 pre-folded)       2,031,616 B
// w1aF, w1bF, c1F : M_*64 f32 each                       3 x 126,976 B
// c2F              : M_*32 f32                           63,488 B
#define W2A_I4     (M_ * 256)                  // int4 elements = 126976
#define OFF_W1A    0
#define OFF_W1B    (M_ * 64)
#define OFF_C1     (M_ * 128)
#define OFF_C2     (M_ * 192)
#define FOLD_FLOATS (M_ * 192 + M_ * 32)       // 111104
#define WS_NEEDED  ((size_t)W2A_I4 * 16 + (size_t)FOLD_FLOATS * 4)

// prep thread ranges
#define NP_OUT  (B_ * CLS_)                    // 20480
#define NP_F1   (M_ * H1_)                     // 31744
#define NP_F2   (M_ * H2_)                     // 15872
#define NP_W2A  (M_ * 256)                     // 126976
#define NP_TOT  (NP_OUT + NP_F1 + NP_F2 + NP_W2A)   // 195072 = 762*256

// ---------------- prep: out-init + BN folds + W2 frag pack ----------------
__global__ __launch_bounds__(256) void k_prep2(
    const float* __restrict__ W1, const float* __restrict__ b1,
    const float* __restrict__ g1, const float* __restrict__ be1,
    const float* __restrict__ m1, const float* __restrict__ v1,
    const float* __restrict__ W2, const float* __restrict__ b2p,
    const float* __restrict__ g2, const float* __restrict__ be2,
    const float* __restrict__ m2, const float* __restrict__ v2,
    const float* __restrict__ bout,
    int4* __restrict__ W2a, float* __restrict__ fold,
    float* __restrict__ out)
{
    int t = blockIdx.x * 256 + threadIdx.x;
    if (t < NP_OUT) {                          // out = bout (atomic targets)
        out[t] = bout[t % CLS_];
        return;
    }
    t -= NP_OUT;
    if (t < NP_F1) {                           // layer-1 fold
        float s = g1[t] * rsqrtf(v1[t] + EPS_);
        fold[OFF_W1A + t] = s * W1[2 * t];
        fold[OFF_W1B + t] = s * W1[2 * t + 1];
        fold[OFF_C1  + t] = fmaf(s, b1[t] - m1[t], be1[t]);
        return;
    }
    t -= NP_F1;
    if (t < NP_F2) {                           // layer-2 c2 fold
        float s = g2[t] * rsqrtf(v2[t] + EPS_);
        fold[OFF_C2 + t] = fmaf(s, b2p[t] - m2[t], be2[t]);
        return;
    }
    t -= NP_F2;
    {   // W2a frag pack with s2 pre-folded. idx = m*256 + u*128 + s*64 + lane
        int lane = t & 63, s = (t >> 6) & 1, u = (t >> 7) & 1, m = t >> 8;
        int q = lane >> 4, ln = lane & 15;
        int n = u * 16 + ln;
        int j = m * H2_ + n;
        float sc = g2[j] * rsqrtf(v2[j] + EPS_);
        const float* p = W2 + m * (H2_ * H1_) + n * H1_ + s * 32 + q * 8;
        float4 f0 = *(const float4*)p;
        float4 f1 = *(const float4*)(p + 4);
        int4 d;
        d.x = ((unsigned)(unsigned short)f2bf(sc * f0.x)) | ((unsigned)(unsigned short)f2bf(sc * f0.y) << 16);
        d.y = ((unsigned)(unsigned short)f2bf(sc * f0.z)) | ((unsigned)(unsigned short)f2bf(sc * f0.w) << 16);
        d.z = ((unsigned)(unsigned short)f2bf(sc * f1.x)) | ((unsigned)(unsigned short)f2bf(sc * f1.y) << 16);
        d.w = ((unsigned)(unsigned short)f2bf(sc * f1.z)) | ((unsigned)(unsigned short)f2bf(sc * f1.w) << 16);
        W2a[t] = d;
    }
}

// ---------------- fused main: MLP + Wout projection, atomic finish ----------------
// grid = (32 b-blocks of 64 batches, 31 m-chunks of 16). block 256 = 4 waves.
// Wave w owns batches bb + w*16 + ln. Per m: h1 in regs (MFMA B-frag layout),
// W2s frags from ws, 4 MFMA -> D[n][b], in-reg n-reduce + 2 shuffles -> o,
// Wout accumulated in regs (classes split across quads), atomicAdd at end.
__global__ __launch_bounds__(256) void k_all(
    const float* __restrict__ x,
    const int4* __restrict__ W2a, const float* __restrict__ fold,
    const float* __restrict__ W3, const float* __restrict__ b3,
    const float* __restrict__ Wout,
    float* __restrict__ out)
{
    __shared__ float xs[64 * 33];              // x slice, stride 33
    __shared__ float wS[16 * CLS_];            // Wout slice [mi][c]

    const int tid = threadIdx.x;
    const int bb  = blockIdx.x * 64;
    const int m0  = blockIdx.y * 16;

    {   // stage x: 64 batches x 32 cols; thread t: row=t>>2, cols (t&3)*8..+7
        int row = tid >> 2, cg = tid & 3;
        const float* p = x + (bb + row) * NC_ + cg * 8;
        float4 f0 = *(const float4*)p;
        float4 f1 = *(const float4*)(p + 4);
        float* d = xs + row * 33 + cg * 8;
        d[0] = f0.x; d[1] = f0.y; d[2] = f0.z; d[3] = f0.w;
        d[4] = f1.x; d[5] = f1.y; d[6] = f1.z; d[7] = f1.w;
    }
    if (tid < 16 * CLS_) {                     // stage Wout slice
        int mi = tid / CLS_, c = tid % CLS_;
        wS[tid] = Wout[c * M_ + m0 + mi];
    }
    __syncthreads();

    const int lane = tid & 63;
    const int w    = tid >> 6;
    const int q    = lane >> 4;
    const int ln   = lane & 15;
    const int brow = w * 16 + ln;              // batch row within block
    const int nc   = (q < 2) ? 3 : 2;          // classes per lane: q, q+4, (q+8)

    int i0, i1;
    pair_of_m(m0, i0, i1);

    float accC[3] = {0.f, 0.f, 0.f};

#pragma unroll 2
    for (int mi = 0; mi < 16; ++mi) {
        const int mm = m0 + mi;

        const float x0 = xs[brow * 33 + i0];
        const float x1 = xs[brow * 33 + i1];

        // fold loads: k = s*32 + q*8 + j (j=0..7, s=0,1)
        const float* fa = fold + OFF_W1A + mm * 64 + q * 8;
        const float* fb = fold + OFF_W1B + mm * 64 + q * 8;
        const float* fc = fold + OFF_C1  + mm * 64 + q * 8;
        F16 A, Bv, C;
        A.v[0]  = *(const float4*)fa;        A.v[1]  = *(const float4*)(fa + 4);
        A.v[2]  = *(const float4*)(fa + 32); A.v[3]  = *(const float4*)(fa + 36);
        Bv.v[0] = *(const float4*)fb;        Bv.v[1] = *(const float4*)(fb + 4);
        Bv.v[2] = *(const float4*)(fb + 32); Bv.v[3] = *(const float4*)(fb + 36);
        C.v[0]  = *(const float4*)fc;        C.v[1]  = *(const float4*)(fc + 4);
        C.v[2]  = *(const float4*)(fc + 32); C.v[3]  = *(const float4*)(fc + 36);

        // h1 B-frags: element j of frag s = h1[k = s*32+q*8+j] for batch brow
        unsigned hw0[4], hw1[4];
#pragma unroll
        for (int jp = 0; jp < 4; ++jp) {
            float he = fmaxf(fmaf(x0, A.f[2*jp],     fmaf(x1, Bv.f[2*jp],     C.f[2*jp])),     0.f);
            float ho = fmaxf(fmaf(x0, A.f[2*jp+1],   fmaf(x1, Bv.f[2*jp+1],   C.f[2*jp+1])),   0.f);
            hw0[jp] = pack_bf2(he, ho);
            float he1 = fmaxf(fmaf(x0, A.f[8+2*jp],  fmaf(x1, Bv.f[8+2*jp],   C.f[8+2*jp])),   0.f);
            float ho1 = fmaxf(fmaf(x0, A.f[8+2*jp+1],fmaf(x1, Bv.f[8+2*jp+1], C.f[8+2*jp+1])), 0.f);
            hw1[jp] = pack_bf2(he1, ho1);
        }
        F8 h0, h1f;
        h0.i  = make_int4(hw0[0], hw0[1], hw0[2], hw0[3]);
        h1f.i = make_int4(hw1[0], hw1[1], hw1[2], hw1[3]);

        // W2s A-frags (s2 pre-folded)
        const int4* wp = W2a + mm * 256 + lane;
        F8 w00, w01, w10, w11;
        w00.i = wp[0];   w01.i = wp[64];
        w10.i = wp[128]; w11.i = wp[192];

        f32x4 acc0 = {0.f, 0.f, 0.f, 0.f};
        f32x4 acc1 = {0.f, 0.f, 0.f, 0.f};
        acc0 = __builtin_amdgcn_mfma_f32_16x16x32_bf16(w00.h, h0.h,  acc0, 0, 0, 0);
        acc0 = __builtin_amdgcn_mfma_f32_16x16x32_bf16(w01.h, h1f.h, acc0, 0, 0, 0);
        acc1 = __builtin_amdgcn_mfma_f32_16x16x32_bf16(w10.h, h0.h,  acc1, 0, 0, 0);
        acc1 = __builtin_amdgcn_mfma_f32_16x16x32_bf16(w11.h, h1f.h, acc1, 0, 0, 0);

        // epilogue: h2 = relu(acc + c2); o = sum h2*w3 (n in quad/reg dims)
        float4 c2lo = *(const float4*)(fold + OFF_C2 + mm * 32 + q * 4);
        float4 c2hi = *(const float4*)(fold + OFF_C2 + mm * 32 + 16 + q * 4);
        float4 w3lo = *(const float4*)(W3 + mm * 32 + q * 4);
        float4 w3hi = *(const float4*)(W3 + mm * 32 + 16 + q * 4);

        float part;
        part = fmaxf(acc0[0] + c2lo.x, 0.f) * w3lo.x;
        part = fmaf(fmaxf(acc0[1] + c2lo.y, 0.f), w3lo.y, part);
        part = fmaf(fmaxf(acc0[2] + c2lo.z, 0.f), w3lo.z, part);
        part = fmaf(fmaxf(acc0[3] + c2lo.w, 0.f), w3lo.w, part);
        part = fmaf(fmaxf(acc1[0] + c2hi.x, 0.f), w3hi.x, part);
        part = fmaf(fmaxf(acc1[1] + c2hi.y, 0.f), w3hi.y, part);
        part = fmaf(fmaxf(acc1[2] + c2hi.z, 0.f), w3hi.z, part);
        part = fmaf(fmaxf(acc1[3] + c2hi.w, 0.f), w3hi.w, part);
        part += __shfl_xor(part, 16, 64);
        part += __shfl_xor(part, 32, 64);

        float o = part + b3[mm];

        // Wout accumulation: lane's classes q, q+4, (q+8 if q<2)
#pragma unroll
        for (int idx = 0; idx < 3; ++idx)
            if (idx < nc)
                accC[idx] = fmaf(o, wS[mi * CLS_ + q + 4 * idx], accC[idx]);

        // advance (i0,i1) to m+1
        if (++i1 == NC_) { ++i0; i1 = i0 + 1; }
    }

    const int bidx = bb + brow;
#pragma unroll
    for (int idx = 0; idx < 3; ++idx)
        if (idx < nc)
            atomicAdd(out + bidx * CLS_ + q + 4 * idx, accC[idx]);
}

// ---------------- workspace-free fallback (known-good) ----------------
__global__ __launch_bounds__(256) void k_fused(
    const float* __restrict__ x,
    const float* __restrict__ W1, const float* __restrict__ b1,
    const float* __restrict__ g1, const float* __restrict__ be1,
    const float* __restrict__ m1, const float* __restrict__ v1,
    const float* __restrict__ W2, const float* __restrict__ b2p,
    const float* __restrict__ g2, const float* __restrict__ be2,
    const float* __restrict__ m2, const float* __restrict__ v2,
    const float* __restrict__ W3, const float* __restrict__ b3,
    const float* __restrict__ Wout, const float* __restrict__ bout,
    float* __restrict__ out)
{
    __shared__ float red[256 * CLS_];
    const int tid = threadIdx.x;
    const int bl  = tid & 7;
    const int mg  = tid >> 3;
    const int b   = blockIdx.x * 8 + bl;

    float acc[CLS_];
#pragma unroll
    for (int c = 0; c < CLS_; ++c) acc[c] = 0.f;

    for (int m = mg; m < M_; m += 32) {
        int i0, i1;
        pair_of_m(m, i0, i1);
        const float x0 = x[b * NC_ + i0];
        const float x1 = x[b * NC_ + i1];
        float h1[H1_];
#pragma unroll
        for (int o = 0; o < H1_; ++o) {
            int j = m * H1_ + o;
            float s = g1[j] * rsqrtf(v1[j] + EPS_);
            float pre = fmaf(x0, s * W1[2 * j],
                        fmaf(x1, s * W1[2 * j + 1],
                             fmaf(s, b1[j] - m1[j], be1[j])));
            h1[o] = fmaxf(pre, 0.f);
        }
        float acc3 = b3[m];
#pragma unroll 2
        for (int o = 0; o < H2_; ++o) {
            int j = m * H2_ + o;
            const float* __restrict__ r = W2 + j * H1_;
            float d = 0.f;
#pragma unroll
            for (int i = 0; i < H1_; ++i) d = fmaf(h1[i], r[i], d);
            float s = g2[j] * rsqrtf(v2[j] + EPS_);
            float h2 = fmaxf(fmaf(s, d + b2p[j] - m2[j], be2[j]), 0.f);
            acc3 = fmaf(h2, W3[j], acc3);
        }
#pragma unroll
        for (int c = 0; c < CLS_; ++c)
            acc[c] = fmaf(acc3, Wout[c * M_ + m], acc[c]);
    }

#pragma unroll
    for (int c = 0; c < CLS_; ++c) red[tid * CLS_ + c] = acc[c];
    __syncthreads();
    if (mg == 0) {
#pragma unroll
        for (int c = 0; c < CLS_; ++c) {
            float s = bout[c];
            for (int g = 0; g < 32; ++g)
                s += red[(g * 8 + bl) * CLS_ + c];
            out[b * CLS_ + c] = s;
        }
    }
}

// ---------------- launch ----------------
extern "C" void kernel_launch(void* const* d_in, const int* in_sizes, int n_in,
                              void* d_out, int out_size, void* d_ws, size_t ws_size,
                              hipStream_t stream)
{
    const float* x    = (const float*)d_in[0];
    // d_in[1] (pair_idx) unused: recomputed on device (dtype-immune).
    const float* W1   = (const float*)d_in[2];
    const float* b1   = (const float*)d_in[3];
    const float* g1   = (const float*)d_in[4];
    const float* be1  = (const float*)d_in[5];
    const float* m1   = (const float*)d_in[6];
    const float* v1   = (const float*)d_in[7];
    const float* W2   = (const float*)d_in[8];
    const float* b2p  = (const float*)d_in[9];
    const float* g2   = (const float*)d_in[10];
    const float* be2  = (const float*)d_in[11];
    const float* m2   = (const float*)d_in[12];
    const float* v2   = (const float*)d_in[13];
    const float* W3   = (const float*)d_in[14];
    const float* b3   = (const float*)d_in[15];
    const float* Wout = (const float*)d_in[16];
    const float* bout = (const float*)d_in[17];
    float* out  = (float*)d_out;
    int4*  W2a  = (int4*)d_ws;
    float* fold = (float*)((char*)d_ws + (size_t)W2A_I4 * 16);

    if (ws_size >= WS_NEEDED) {
        k_prep2<<<NP_TOT / 256, 256, 0, stream>>>(
            W1, b1, g1, be1, m1, v1, W2, b2p, g2, be2, m2, v2,
            bout, W2a, fold, out);
        k_all<<<dim3(B_ / 64, M_ / 16), 256, 0, stream>>>(
            x, W2a, fold, W3, b3, Wout, out);
    } else {
        k_fused<<<B_ / 8, 256, 0, stream>>>(
            x, W1, b1, g1, be1, m1, v1,
            W2, b2p, g2, be2, m2, v2, W3, b3, Wout, bout, out);
    }
}

// Round 9
// 128.752 us; speedup vs baseline: 1.0544x; 1.0544x over previous
//
#include <hip/hip_runtime.h>
#include <hip/hip_bf16.h>

// Problem constants
#define B_    2048
#define NC_   32
#define H1_   64
#define H2_   32
#define CLS_  10
#define M_    496
#define EPS_  1e-5f

typedef __attribute__((ext_vector_type(8))) short bf16x8;  // 8 bf16 (4 VGPRs)
typedef __attribute__((ext_vector_type(4))) float f32x4;   // MFMA C/D

union F8 { int4 i; bf16x8 h; };

// float -> bf16 (RNE)
__device__ __forceinline__ short f2bf(float f) {
    unsigned u = __float_as_uint(f);
    u = (u + 0x7FFFu + ((u >> 16) & 1u)) >> 16;
    return (short)u;
}

// pack two floats' bf16(round-half-up) into one dword: low=e, high=o.
__device__ __forceinline__ unsigned pack_bf2(float e, float o) {
    unsigned ue = __float_as_uint(e) + 0x8000u;
    unsigned uo = __float_as_uint(o) + 0x8000u;
    return __builtin_amdgcn_perm(uo, ue, 0x07060302u);
}

// m -> (i0,i1): lexicographic pair from combinations(range(32),2).
__device__ __forceinline__ void pair_of_m(int m, int& i0, int& i1) {
    int a = 0, rem = m;
    while (rem >= (NC_ - 1 - a)) { rem -= (NC_ - 1 - a); ++a; }
    i0 = a; i1 = a + 1 + rem;
}

#define OBUF_BYTES  ((size_t)M_ * B_ * 4)                  // 4,063,232

// ---------------- main kernel (r7 structure, inline W2 cvt, out-init) ----------------
// grid = (M_, 4), block = 256 (4 waves). Wave w: 128 batches = 2 halves x 4 tiles x 16.
// MFMA roles: A = W2 [n x k], B = h1 [k x b]  ->  D[n][b].
// Blocks with blockIdx.x==0 also initialize out = bout (for k_outa's atomics).
__global__ __launch_bounds__(256) void k_main3(
    const float* __restrict__ x,
    const float* __restrict__ W1, const float* __restrict__ b1,
    const float* __restrict__ g1, const float* __restrict__ be1,
    const float* __restrict__ m1, const float* __restrict__ v1,
    const float* __restrict__ W2, const float* __restrict__ b2p,
    const float* __restrict__ g2, const float* __restrict__ be2,
    const float* __restrict__ m2, const float* __restrict__ v2,
    const float* __restrict__ W3, const float* __restrict__ b3,
    const float* __restrict__ bout,
    float* __restrict__ obuf, float* __restrict__ out)
{
    __shared__ float w1aS[H1_], w1bS[H1_], c1S[H1_];
    __shared__ float s2S[H2_], c2S[H2_], w3S[H2_];
    __shared__ float xs0[512], xs1[512];

    const int m   = blockIdx.x;
    const int tid = threadIdx.x;

    // out = bout init (next kernel accumulates atomically on top)
    if (m == 0) {
        const int base = blockIdx.y * (B_ / 4) * CLS_;   // 5120 per y
#pragma unroll
        for (int k = 0; k < (B_ / 4) * CLS_ / 256; ++k) {
            int idx = tid + k * 256;
            out[base + idx] = bout[idx % CLS_];
        }
    }

    int i0, i1;
    pair_of_m(m, i0, i1);

    if (tid < H1_) {                               // layer-1 BN fold
        int j = m * H1_ + tid;
        float s = g1[j] * rsqrtf(v1[j] + EPS_);
        w1aS[tid] = s * W1[2 * j];
        w1bS[tid] = s * W1[2 * j + 1];
        c1S[tid]  = fmaf(s, b1[j] - m1[j], be1[j]);
    } else if (tid < H1_ + H2_) {                  // layer-2 BN fold
        int o = tid - H1_;
        int j = m * H2_ + o;
        float s = g2[j] * rsqrtf(v2[j] + EPS_);
        s2S[o] = s;
        c2S[o] = fmaf(s, b2p[j] - m2[j], be2[j]);
        w3S[o] = W3[j];
    }
    {   // stage x columns for this block's 512 batches
        int bb = blockIdx.y * 512;
        xs0[tid]       = x[(bb + tid) * NC_ + i0];
        xs1[tid]       = x[(bb + tid) * NC_ + i1];
        xs0[256 + tid] = x[(bb + 256 + tid) * NC_ + i0];
        xs1[256 + tid] = x[(bb + 256 + tid) * NC_ + i1];
    }
    __syncthreads();

    const int lane = tid & 63;
    const int w    = tid >> 6;
    const int q    = lane >> 4;
    const int ln   = lane & 15;
    const int wbase = w * 128;                     // batch offset within block
    const float b3m = b3[m];

    // ---- W2 fragments (A operand), inline f32->bf16 cvt ----
    F8 wfr[2][2];
    {
        const float* W2m = W2 + m * (H2_ * H1_);
#pragma unroll
        for (int u = 0; u < 2; ++u)
#pragma unroll
            for (int s = 0; s < 2; ++s) {
                const float* p = W2m + (u * 16 + ln) * H1_ + s * 32 + q * 8;
                float4 f0 = *(const float4*)p;
                float4 f1 = *(const float4*)(p + 4);
                int4 d;
                d.x = (unsigned)(unsigned short)f2bf(f0.x) | ((unsigned)(unsigned short)f2bf(f0.y) << 16);
                d.y = (unsigned)(unsigned short)f2bf(f0.z) | ((unsigned)(unsigned short)f2bf(f0.w) << 16);
                d.z = (unsigned)(unsigned short)f2bf(f1.x) | ((unsigned)(unsigned short)f2bf(f1.y) << 16);
                d.w = (unsigned)(unsigned short)f2bf(f1.z) | ((unsigned)(unsigned short)f2bf(f1.w) << 16);
                wfr[u][s].i = d;
            }
    }

    // ---- epilogue constants (per-lane n-slots) ----
    float s2a0[4], c2a0[4], w3a0[4], s2a1[4], c2a1[4], w3a1[4];
#pragma unroll
    for (int r = 0; r < 4; ++r) {
        int n0 = q * 4 + r, n1 = 16 + n0;
        s2a0[r] = s2S[n0]; c2a0[r] = c2S[n0]; w3a0[r] = w3S[n0];
        s2a1[r] = s2S[n1]; c2a1[r] = c2S[n1]; w3a1[r] = w3S[n1];
    }

#pragma unroll
    for (int h = 0; h < 2; ++h) {
        const int hbase = wbase + h * 64;

        float x0v[4], x1v[4];
#pragma unroll
        for (int t = 0; t < 4; ++t) {
            x0v[t] = xs0[hbase + t * 16 + ln];
            x1v[t] = xs1[hbase + t * 16 + ln];
        }

        // ---- h1 fragments (B operand): k = s*32 + q*8 + j ----
        F8 hfr[4][2];
#pragma unroll
        for (int s = 0; s < 2; ++s)
#pragma unroll
            for (int jp = 0; jp < 4; ++jp) {
                int ke = s * 32 + q * 8 + 2 * jp;
                float wae = w1aS[ke],     wbe = w1bS[ke],     ce = c1S[ke];
                float wao = w1aS[ke + 1], wbo = w1bS[ke + 1], co = c1S[ke + 1];
                unsigned dw[4];
#pragma unroll
                for (int t = 0; t < 4; ++t) {
                    float he = fmaxf(fmaf(x0v[t], wae, fmaf(x1v[t], wbe, ce)), 0.f);
                    float ho = fmaxf(fmaf(x0v[t], wao, fmaf(x1v[t], wbo, co)), 0.f);
                    dw[t] = pack_bf2(he, ho);
                }
                hfr[0][s].i[jp] = dw[0];  hfr[1][s].i[jp] = dw[1];
                hfr[2][s].i[jp] = dw[2];  hfr[3][s].i[jp] = dw[3];
            }

        // ---- MFMA + epilogue ----
        float ot[4];
#pragma unroll
        for (int t = 0; t < 4; ++t) {
            f32x4 acc0 = {0.f, 0.f, 0.f, 0.f};
            f32x4 acc1 = {0.f, 0.f, 0.f, 0.f};
            acc0 = __builtin_amdgcn_mfma_f32_16x16x32_bf16(wfr[0][0].h, hfr[t][0].h, acc0, 0, 0, 0);
            acc0 = __builtin_amdgcn_mfma_f32_16x16x32_bf16(wfr[0][1].h, hfr[t][1].h, acc0, 0, 0, 0);
            acc1 = __builtin_amdgcn_mfma_f32_16x16x32_bf16(wfr[1][0].h, hfr[t][0].h, acc1, 0, 0, 0);
            acc1 = __builtin_amdgcn_mfma_f32_16x16x32_bf16(wfr[1][1].h, hfr[t][1].h, acc1, 0, 0, 0);

            float part = 0.f;
#pragma unroll
            for (int r = 0; r < 4; ++r) {
                float h20 = fmaxf(fmaf(s2a0[r], acc0[r], c2a0[r]), 0.f);
                float h21 = fmaxf(fmaf(s2a1[r], acc1[r], c2a1[r]), 0.f);
                part = fmaf(h20, w3a0[r], fmaf(h21, w3a1[r], part));
            }
            part += __shfl_xor(part, 16, 64);
            part += __shfl_xor(part, 32, 64);
            ot[t] = part;
        }

        // quad q stores tile t=q -> one coalesced 256B store per wave per half
        float o = (q == 0) ? ot[0] : (q == 1) ? ot[1] : (q == 2) ? ot[2] : ot[3];
        obuf[m * B_ + blockIdx.y * 512 + hbase + lane] = o + b3m;
    }
}

// ---------------- output projection: partial + atomic finish ----------------
// grid = (32 b-tiles, 16 m-chunks of 31). block 256 = 64 b-lanes x 4 m-groups.
// out was pre-initialized to bout by k_main3; 16 chunks atomically accumulate.
__global__ __launch_bounds__(256) void k_outa(
    const float* __restrict__ obuf, const float* __restrict__ Wout,
    float* __restrict__ out)
{
    __shared__ float red[256 * CLS_];
    const int tid = threadIdx.x;
    const int bl  = tid & 63;
    const int mg  = tid >> 6;
    const int b   = blockIdx.x * 64 + bl;
    const int mb  = blockIdx.y * 31;

    float acc[CLS_];
#pragma unroll
    for (int c = 0; c < CLS_; ++c) acc[c] = 0.f;

    for (int i = mg; i < 31; i += 4) {
        int m = mb + i;
        float o = obuf[m * B_ + b];
#pragma unroll
        for (int c = 0; c < CLS_; ++c)
            acc[c] = fmaf(o, Wout[c * M_ + m], acc[c]);
    }
#pragma unroll
    for (int c = 0; c < CLS_; ++c) red[tid * CLS_ + c] = acc[c];
    __syncthreads();

    if (mg == 0) {
#pragma unroll
        for (int c = 0; c < CLS_; ++c) {
            float s = red[(0 * 64 + bl) * CLS_ + c] + red[(1 * 64 + bl) * CLS_ + c]
                    + red[(2 * 64 + bl) * CLS_ + c] + red[(3 * 64 + bl) * CLS_ + c];
            atomicAdd(out + b * CLS_ + c, s);
        }
    }
}

// ---------------- workspace-free fallback (known-good) ----------------
__global__ __launch_bounds__(256) void k_fused(
    const float* __restrict__ x,
    const float* __restrict__ W1, const float* __restrict__ b1,
    const float* __restrict__ g1, const float* __restrict__ be1,
    const float* __restrict__ m1, const float* __restrict__ v1,
    const float* __restrict__ W2, const float* __restrict__ b2p,
    const float* __restrict__ g2, const float* __restrict__ be2,
    const float* __restrict__ m2, const float* __restrict__ v2,
    const float* __restrict__ W3, const float* __restrict__ b3,
    const float* __restrict__ Wout, const float* __restrict__ bout,
    float* __restrict__ out)
{
    __shared__ float red[256 * CLS_];
    const int tid = threadIdx.x;
    const int bl  = tid & 7;
    const int mg  = tid >> 3;
    const int b   = blockIdx.x * 8 + bl;

    float acc[CLS_];
#pragma unroll
    for (int c = 0; c < CLS_; ++c) acc[c] = 0.f;

    for (int m = mg; m < M_; m += 32) {
        int i0, i1;
        pair_of_m(m, i0, i1);
        const float x0 = x[b * NC_ + i0];
        const float x1 = x[b * NC_ + i1];
        float h1[H1_];
#pragma unroll
        for (int o = 0; o < H1_; ++o) {
            int j = m * H1_ + o;
            float s = g1[j] * rsqrtf(v1[j] + EPS_);
            float pre = fmaf(x0, s * W1[2 * j],
                        fmaf(x1, s * W1[2 * j + 1],
                             fmaf(s, b1[j] - m1[j], be1[j])));
            h1[o] = fmaxf(pre, 0.f);
        }
        float acc3 = b3[m];
#pragma unroll 2
        for (int o = 0; o < H2_; ++o) {
            int j = m * H2_ + o;
            const float* __restrict__ r = W2 + j * H1_;
            float d = 0.f;
#pragma unroll
            for (int i = 0; i < H1_; ++i) d = fmaf(h1[i], r[i], d);
            float s = g2[j] * rsqrtf(v2[j] + EPS_);
            float h2 = fmaxf(fmaf(s, d + b2p[j] - m2[j], be2[j]), 0.f);
            acc3 = fmaf(h2, W3[j], acc3);
        }
#pragma unroll
        for (int c = 0; c < CLS_; ++c)
            acc[c] = fmaf(acc3, Wout[c * M_ + m], acc[c]);
    }

#pragma unroll
    for (int c = 0; c < CLS_; ++c) red[tid * CLS_ + c] = acc[c];
    __syncthreads();
    if (mg == 0) {
#pragma unroll
        for (int c = 0; c < CLS_; ++c) {
            float s = bout[c];
            for (int g = 0; g < 32; ++g)
                s += red[(g * 8 + bl) * CLS_ + c];
            out[b * CLS_ + c] = s;
        }
    }
}

// ---------------- launch ----------------
extern "C" void kernel_launch(void* const* d_in, const int* in_sizes, int n_in,
                              void* d_out, int out_size, void* d_ws, size_t ws_size,
                              hipStream_t stream)
{
    const float* x    = (const float*)d_in[0];
    // d_in[1] (pair_idx) unused: recomputed on device (dtype-immune).
    const float* W1   = (const float*)d_in[2];
    const float* b1   = (const float*)d_in[3];
    const float* g1   = (const float*)d_in[4];
    const float* be1  = (const float*)d_in[5];
    const float* m1   = (const float*)d_in[6];
    const float* v1   = (const float*)d_in[7];
    const float* W2   = (const float*)d_in[8];
    const float* b2p  = (const float*)d_in[9];
    const float* g2   = (const float*)d_in[10];
    const float* be2  = (const float*)d_in[11];
    const float* m2   = (const float*)d_in[12];
    const float* v2   = (const float*)d_in[13];
    const float* W3   = (const float*)d_in[14];
    const float* b3   = (const float*)d_in[15];
    const float* Wout = (const float*)d_in[16];
    const float* bout = (const float*)d_in[17];
    float* out  = (float*)d_out;
    float* obuf = (float*)d_ws;

    if (ws_size >= OBUF_BYTES) {
        k_main3<<<dim3(M_, B_ / 512), 256, 0, stream>>>(
            x, W1, b1, g1, be1, m1, v1, W2, b2p, g2, be2, m2, v2,
            W3, b3, bout, obuf, out);
        k_outa<<<dim3(B_ / 64, 16), 256, 0, stream>>>(obuf, Wout, out);
    } else {
        k_fused<<<B_ / 8, 256, 0, stream>>>(
            x, W1, b1, g1, be1, m1, v1,
            W2, b2p, g2, be2, m2, v2, W3, b3, Wout, bout, out);
    }
}

// Round 10
// 126.249 us; speedup vs baseline: 1.0753x; 1.0198x over previous
//
#include <hip/hip_runtime.h>
#include <hip/hip_bf16.h>

// Problem constants
#define B_    2048
#define NC_   32
#define H1_   64
#define H2_   32
#define CLS_  10
#define M_    496
#define EPS_  1e-5f

typedef __attribute__((ext_vector_type(8))) short bf16x8;  // 8 bf16 (4 VGPRs)
typedef __attribute__((ext_vector_type(4))) float f32x4;   // MFMA C/D

union F8 { int4 i; bf16x8 h; };

// float -> bf16 (RNE)
__device__ __forceinline__ short f2bf(float f) {
    unsigned u = __float_as_uint(f);
    u = (u + 0x7FFFu + ((u >> 16) & 1u)) >> 16;
    return (short)u;
}

// pack two floats' bf16(round-half-up) into one dword: low=e, high=o.
__device__ __forceinline__ unsigned pack_bf2(float e, float o) {
    unsigned ue = __float_as_uint(e) + 0x8000u;
    unsigned uo = __float_as_uint(o) + 0x8000u;
    return __builtin_amdgcn_perm(uo, ue, 0x07060302u);
}

// m -> (i0,i1): lexicographic pair from combinations(range(32),2).
__device__ __forceinline__ void pair_of_m(int m, int& i0, int& i1) {
    int a = 0, rem = m;
    while (rem >= (NC_ - 1 - a)) { rem -= (NC_ - 1 - a); ++a; }
    i0 = a; i1 = a + 1 + rem;
}

// ws layout (bytes)
#define OBUF_BYTES  ((size_t)M_ * B_ * 4)                  // 4,063,232
#define W2A_BYTES   ((size_t)M_ * 2 * 2 * 64 * 16)         // 2,031,616

// prep thread ranges
#define NP_OUT  (B_ * CLS_)                                // 20480
#define NP_W2A  (M_ * 256)                                 // 126976
#define NP_TOT  (NP_OUT + NP_W2A)                          // 147456 = 576*256

// ---------------- prep: out-init + W2 -> bf16 MFMA-fragment pack ----------------
// frag index ((m*2+u)*2+s)*64 + lane ; lane=(q,ln): holds W2[m][u*16+ln][s*32+q*8 .. +7]
__global__ __launch_bounds__(256) void k_prep3(
    const float* __restrict__ W2, const float* __restrict__ bout,
    int4* __restrict__ W2a, float* __restrict__ out)
{
    int t = blockIdx.x * 256 + threadIdx.x;
    if (t < NP_OUT) {                          // out = bout (atomic targets)
        out[t] = bout[t % CLS_];
        return;
    }
    t -= NP_OUT;
    int lane = t & 63, s = (t >> 6) & 1, u = (t >> 7) & 1, m = t >> 8;
    int q = lane >> 4, ln = lane & 15;
    const float* p = W2 + m * (H2_ * H1_) + (u * 16 + ln) * H1_ + s * 32 + q * 8;
    float4 f0 = *(const float4*)p;
    float4 f1 = *(const float4*)(p + 4);
    int4 d;
    d.x = ((unsigned)(unsigned short)f2bf(f0.x)) | ((unsigned)(unsigned short)f2bf(f0.y) << 16);
    d.y = ((unsigned)(unsigned short)f2bf(f0.z)) | ((unsigned)(unsigned short)f2bf(f0.w) << 16);
    d.z = ((unsigned)(unsigned short)f2bf(f1.x)) | ((unsigned)(unsigned short)f2bf(f1.y) << 16);
    d.w = ((unsigned)(unsigned short)f2bf(f1.z)) | ((unsigned)(unsigned short)f2bf(f1.w) << 16);
    W2a[t] = d;
}

// ---------------- main kernel (r7-identical) ----------------
// grid = (M_, 4), block = 256 (4 waves). Wave w: 128 batches = 2 halves x 4 tiles x 16.
// MFMA roles: A = W2 [n x k], B = h1 [k x b]  ->  D[n][b].
template <bool PREP>
__global__ __launch_bounds__(256) void k_main3(
    const float* __restrict__ x,
    const float* __restrict__ W1, const float* __restrict__ b1,
    const float* __restrict__ g1, const float* __restrict__ be1,
    const float* __restrict__ m1, const float* __restrict__ v1,
    const float* __restrict__ W2, const int4* __restrict__ W2a,
    const float* __restrict__ b2p,
    const float* __restrict__ g2, const float* __restrict__ be2,
    const float* __restrict__ m2, const float* __restrict__ v2,
    const float* __restrict__ W3, const float* __restrict__ b3,
    float* __restrict__ obuf)
{
    __shared__ float w1aS[H1_], w1bS[H1_], c1S[H1_];
    __shared__ float s2S[H2_], c2S[H2_], w3S[H2_];
    __shared__ float xs0[512], xs1[512];

    const int m   = blockIdx.x;
    const int tid = threadIdx.x;

    int i0, i1;
    pair_of_m(m, i0, i1);

    if (tid < H1_) {                               // layer-1 BN fold
        int j = m * H1_ + tid;
        float s = g1[j] * rsqrtf(v1[j] + EPS_);
        w1aS[tid] = s * W1[2 * j];
        w1bS[tid] = s * W1[2 * j + 1];
        c1S[tid]  = fmaf(s, b1[j] - m1[j], be1[j]);
    } else if (tid < H1_ + H2_) {                  // layer-2 BN fold
        int o = tid - H1_;
        int j = m * H2_ + o;
        float s = g2[j] * rsqrtf(v2[j] + EPS_);
        s2S[o] = s;
        c2S[o] = fmaf(s, b2p[j] - m2[j], be2[j]);
        w3S[o] = W3[j];
    }
    {   // stage x columns for this block's 512 batches
        int bb = blockIdx.y * 512;
        xs0[tid]       = x[(bb + tid) * NC_ + i0];
        xs1[tid]       = x[(bb + tid) * NC_ + i1];
        xs0[256 + tid] = x[(bb + 256 + tid) * NC_ + i0];
        xs1[256 + tid] = x[(bb + 256 + tid) * NC_ + i1];
    }
    __syncthreads();

    const int lane = tid & 63;
    const int w    = tid >> 6;
    const int q    = lane >> 4;
    const int ln   = lane & 15;
    const int wbase = w * 128;                     // batch offset within block
    const float b3m = b3[m];

    // ---- W2 fragments (A operand): wfr[u][s] ----
    F8 wfr[2][2];
    if (PREP) {
        const int4* p = W2a + (m * 4) * 64 + lane;
#pragma unroll
        for (int u = 0; u < 2; ++u)
#pragma unroll
            for (int s = 0; s < 2; ++s)
                wfr[u][s].i = p[(u * 2 + s) * 64];
    } else {
        const float* W2m = W2 + m * (H2_ * H1_);
#pragma unroll
        for (int u = 0; u < 2; ++u)
#pragma unroll
            for (int s = 0; s < 2; ++s) {
                const float* p = W2m + (u * 16 + ln) * H1_ + s * 32 + q * 8;
                float4 f0 = *(const float4*)p;
                float4 f1 = *(const float4*)(p + 4);
                int4 d;
                d.x = ((unsigned)(unsigned short)f2bf(f0.x)) | ((unsigned)(unsigned short)f2bf(f0.y) << 16);
                d.y = ((unsigned)(unsigned short)f2bf(f0.z)) | ((unsigned)(unsigned short)f2bf(f0.w) << 16);
                d.z = ((unsigned)(unsigned short)f2bf(f1.x)) | ((unsigned)(unsigned short)f2bf(f1.y) << 16);
                d.w = ((unsigned)(unsigned short)f2bf(f1.z)) | ((unsigned)(unsigned short)f2bf(f1.w) << 16);
                wfr[u][s].i = d;
            }
    }

    // ---- epilogue constants (per-lane n-slots) ----
    float s2a0[4], c2a0[4], w3a0[4], s2a1[4], c2a1[4], w3a1[4];
#pragma unroll
    for (int r = 0; r < 4; ++r) {
        int n0 = q * 4 + r, n1 = 16 + n0;
        s2a0[r] = s2S[n0]; c2a0[r] = c2S[n0]; w3a0[r] = w3S[n0];
        s2a1[r] = s2S[n1]; c2a1[r] = c2S[n1]; w3a1[r] = w3S[n1];
    }

#pragma unroll
    for (int h = 0; h < 2; ++h) {
        const int hbase = wbase + h * 64;

        float x0v[4], x1v[4];
#pragma unroll
        for (int t = 0; t < 4; ++t) {
            x0v[t] = xs0[hbase + t * 16 + ln];
            x1v[t] = xs1[hbase + t * 16 + ln];
        }

        // ---- h1 fragments (B operand): k = s*32 + q*8 + j ----
        F8 hfr[4][2];
#pragma unroll
        for (int s = 0; s < 2; ++s)
#pragma unroll
            for (int jp = 0; jp < 4; ++jp) {
                int ke = s * 32 + q * 8 + 2 * jp;
                float wae = w1aS[ke],     wbe = w1bS[ke],     ce = c1S[ke];
                float wao = w1aS[ke + 1], wbo = w1bS[ke + 1], co = c1S[ke + 1];
                unsigned dw[4];
#pragma unroll
                for (int t = 0; t < 4; ++t) {
                    float he = fmaxf(fmaf(x0v[t], wae, fmaf(x1v[t], wbe, ce)), 0.f);
                    float ho = fmaxf(fmaf(x0v[t], wao, fmaf(x1v[t], wbo, co)), 0.f);
                    dw[t] = pack_bf2(he, ho);
                }
                hfr[0][s].i[jp] = dw[0];  hfr[1][s].i[jp] = dw[1];
                hfr[2][s].i[jp] = dw[2];  hfr[3][s].i[jp] = dw[3];
            }

        // ---- MFMA + epilogue ----
        float ot[4];
#pragma unroll
        for (int t = 0; t < 4; ++t) {
            f32x4 acc0 = {0.f, 0.f, 0.f, 0.f};
            f32x4 acc1 = {0.f, 0.f, 0.f, 0.f};
            acc0 = __builtin_amdgcn_mfma_f32_16x16x32_bf16(wfr[0][0].h, hfr[t][0].h, acc0, 0, 0, 0);
            acc0 = __builtin_amdgcn_mfma_f32_16x16x32_bf16(wfr[0][1].h, hfr[t][1].h, acc0, 0, 0, 0);
            acc1 = __builtin_amdgcn_mfma_f32_16x16x32_bf16(wfr[1][0].h, hfr[t][0].h, acc1, 0, 0, 0);
            acc1 = __builtin_amdgcn_mfma_f32_16x16x32_bf16(wfr[1][1].h, hfr[t][1].h, acc1, 0, 0, 0);

            float part = 0.f;
#pragma unroll
            for (int r = 0; r < 4; ++r) {
                float h20 = fmaxf(fmaf(s2a0[r], acc0[r], c2a0[r]), 0.f);
                float h21 = fmaxf(fmaf(s2a1[r], acc1[r], c2a1[r]), 0.f);
                part = fmaf(h20, w3a0[r], fmaf(h21, w3a1[r], part));
            }
            part += __shfl_xor(part, 16, 64);
            part += __shfl_xor(part, 32, 64);
            ot[t] = part;
        }

        // quad q stores tile t=q -> one coalesced 256B store per wave per half
        float o = (q == 0) ? ot[0] : (q == 1) ? ot[1] : (q == 2) ? ot[2] : ot[3];
        obuf[m * B_ + blockIdx.y * 512 + hbase + lane] = o + b3m;
    }
}

// ---------------- output projection: partials + atomic finish ----------------
// grid = (32 b-tiles, 16 m-chunks of 31). block 256 = 64 b-lanes x 4 m-groups.
// out pre-initialized to bout by k_prep3; 16 chunks accumulate atomically.
__global__ __launch_bounds__(256) void k_outa(
    const float* __restrict__ obuf, const float* __restrict__ Wout,
    float* __restrict__ out)
{
    __shared__ float red[256 * CLS_];
    const int tid = threadIdx.x;
    const int bl  = tid & 63;
    const int mg  = tid >> 6;
    const int b   = blockIdx.x * 64 + bl;
    const int mb  = blockIdx.y * 31;

    float acc[CLS_];
#pragma unroll
    for (int c = 0; c < CLS_; ++c) acc[c] = 0.f;

    for (int i = mg; i < 31; i += 4) {
        int m = mb + i;
        float o = obuf[m * B_ + b];
#pragma unroll
        for (int c = 0; c < CLS_; ++c)
            acc[c] = fmaf(o, Wout[c * M_ + m], acc[c]);
    }
#pragma unroll
    for (int c = 0; c < CLS_; ++c) red[tid * CLS_ + c] = acc[c];
    __syncthreads();

    if (mg == 0) {
#pragma unroll
        for (int c = 0; c < CLS_; ++c) {
            float s = red[(0 * 64 + bl) * CLS_ + c] + red[(1 * 64 + bl) * CLS_ + c]
                    + red[(2 * 64 + bl) * CLS_ + c] + red[(3 * 64 + bl) * CLS_ + c];
            atomicAdd(out + b * CLS_ + c, s);
        }
    }
}

// ---------------- mid-tier single-stage k_out (obuf-only ws) ----------------
__global__ __launch_bounds__(256) void k_out1(
    const float* __restrict__ obuf, const float* __restrict__ Wout,
    const float* __restrict__ bout, float* __restrict__ out)
{
    __shared__ float red[256 * CLS_];
    const int tid = threadIdx.x;
    const int bl  = tid & 31;
    const int mg  = tid >> 5;
    const int b   = blockIdx.x * 32 + bl;

    float acc[CLS_];
#pragma unroll
    for (int c = 0; c < CLS_; ++c) acc[c] = 0.f;
#pragma unroll 4
    for (int m = mg; m < M_; m += 8) {
        float o = obuf[m * B_ + b];
#pragma unroll
        for (int c = 0; c < CLS_; ++c)
            acc[c] = fmaf(o, Wout[c * M_ + m], acc[c]);
    }
#pragma unroll
    for (int c = 0; c < CLS_; ++c) red[tid * CLS_ + c] = acc[c];
    __syncthreads();
    if (mg == 0) {
#pragma unroll
        for (int c = 0; c < CLS_; ++c) {
            float s = bout[c];
#pragma unroll
            for (int g = 0; g < 8; ++g)
                s += red[(g * 32 + bl) * CLS_ + c];
            out[b * CLS_ + c] = s;
        }
    }
}

// ---------------- workspace-free fallback (known-good) ----------------
__global__ __launch_bounds__(256) void k_fused(
    const float* __restrict__ x,
    const float* __restrict__ W1, const float* __restrict__ b1,
    const float* __restrict__ g1, const float* __restrict__ be1,
    const float* __restrict__ m1, const float* __restrict__ v1,
    const float* __restrict__ W2, const float* __restrict__ b2p,
    const float* __restrict__ g2, const float* __restrict__ be2,
    const float* __restrict__ m2, const float* __restrict__ v2,
    const float* __restrict__ W3, const float* __restrict__ b3,
    const float* __restrict__ Wout, const float* __restrict__ bout,
    float* __restrict__ out)
{
    __shared__ float red[256 * CLS_];
    const int tid = threadIdx.x;
    const int bl  = tid & 7;
    const int mg  = tid >> 3;
    const int b   = blockIdx.x * 8 + bl;

    float acc[CLS_];
#pragma unroll
    for (int c = 0; c < CLS_; ++c) acc[c] = 0.f;

    for (int m = mg; m < M_; m += 32) {
        int i0, i1;
        pair_of_m(m, i0, i1);
        const float x0 = x[b * NC_ + i0];
        const float x1 = x[b * NC_ + i1];
        float h1[H1_];
#pragma unroll
        for (int o = 0; o < H1_; ++o) {
            int j = m * H1_ + o;
            float s = g1[j] * rsqrtf(v1[j] + EPS_);
            float pre = fmaf(x0, s * W1[2 * j],
                        fmaf(x1, s * W1[2 * j + 1],
                             fmaf(s, b1[j] - m1[j], be1[j])));
            h1[o] = fmaxf(pre, 0.f);
        }
        float acc3 = b3[m];
#pragma unroll 2
        for (int o = 0; o < H2_; ++o) {
            int j = m * H2_ + o;
            const float* __restrict__ r = W2 + j * H1_;
            float d = 0.f;
#pragma unroll
            for (int i = 0; i < H1_; ++i) d = fmaf(h1[i], r[i], d);
            float s = g2[j] * rsqrtf(v2[j] + EPS_);
            float h2 = fmaxf(fmaf(s, d + b2p[j] - m2[j], be2[j]), 0.f);
            acc3 = fmaf(h2, W3[j], acc3);
        }
#pragma unroll
        for (int c = 0; c < CLS_; ++c)
            acc[c] = fmaf(acc3, Wout[c * M_ + m], acc[c]);
    }

#pragma unroll
    for (int c = 0; c < CLS_; ++c) red[tid * CLS_ + c] = acc[c];
    __syncthreads();
    if (mg == 0) {
#pragma unroll
        for (int c = 0; c < CLS_; ++c) {
            float s = bout[c];
            for (int g = 0; g < 32; ++g)
                s += red[(g * 8 + bl) * CLS_ + c];
            out[b * CLS_ + c] = s;
        }
    }
}

// ---------------- launch ----------------
extern "C" void kernel_launch(void* const* d_in, const int* in_sizes, int n_in,
                              void* d_out, int out_size, void* d_ws, size_t ws_size,
                              hipStream_t stream)
{
    const float* x    = (const float*)d_in[0];
    // d_in[1] (pair_idx) unused: recomputed on device (dtype-immune).
    const float* W1   = (const float*)d_in[2];
    const float* b1   = (const float*)d_in[3];
    const float* g1   = (const float*)d_in[4];
    const float* be1  = (const float*)d_in[5];
    const float* m1   = (const float*)d_in[6];
    const float* v1   = (const float*)d_in[7];
    const float* W2   = (const float*)d_in[8];
    const float* b2p  = (const float*)d_in[9];
    const float* g2   = (const float*)d_in[10];
    const float* be2  = (const float*)d_in[11];
    const float* m2   = (const float*)d_in[12];
    const float* v2   = (const float*)d_in[13];
    const float* W3   = (const float*)d_in[14];
    const float* b3   = (const float*)d_in[15];
    const float* Wout = (const float*)d_in[16];
    const float* bout = (const float*)d_in[17];
    float* out  = (float*)d_out;
    float* obuf = (float*)d_ws;
    int4*  W2a  = (int4*)((char*)d_ws + OBUF_BYTES);

    if (ws_size >= OBUF_BYTES + W2A_BYTES) {
        k_prep3<<<NP_TOT / 256, 256, 0, stream>>>(W2, bout, W2a, out);
        k_main3<true><<<dim3(M_, B_ / 512), 256, 0, stream>>>(
            x, W1, b1, g1, be1, m1, v1, W2, W2a,
            b2p, g2, be2, m2, v2, W3, b3, obuf);
        k_outa<<<dim3(B_ / 64, 16), 256, 0, stream>>>(obuf, Wout, out);
    } else if (ws_size >= OBUF_BYTES) {
        k_main3<false><<<dim3(M_, B_ / 512), 256, 0, stream>>>(
            x, W1, b1, g1, be1, m1, v1, W2, (const int4*)nullptr,
            b2p, g2, be2, m2, v2, W3, b3, obuf);
        k_out1<<<B_ / 32, 256, 0, stream>>>(obuf, Wout, bout, out);
    } else {
        k_fused<<<B_ / 8, 256, 0, stream>>>(
            x, W1, b1, g1, be1, m1, v1,
            W2, b2p, g2, be2, m2, v2, W3, b3, Wout, bout, out);
    }
}

// Round 11
// 116.472 us; speedup vs baseline: 1.1656x; 1.0839x over previous
//
#include <hip/hip_runtime.h>
#include <hip/hip_bf16.h>

// Problem constants
#define B_    2048
#define NC_   32
#define H1_   64
#define H2_   32
#define CLS_  10
#define M_    496
#define EPS_  1e-5f

typedef __attribute__((ext_vector_type(8))) short bf16x8;  // 8 bf16 (4 VGPRs)
typedef __attribute__((ext_vector_type(4))) float f32x4;   // MFMA C/D

union F8 { int4 i; bf16x8 h; };

// float -> bf16 (RNE)
__device__ __forceinline__ short f2bf(float f) {
    unsigned u = __float_as_uint(f);
    u = (u + 0x7FFFu + ((u >> 16) & 1u)) >> 16;
    return (short)u;
}

// pack two floats' bf16(round-half-up) into one dword: low=e, high=o.
__device__ __forceinline__ unsigned pack_bf2(float e, float o) {
    unsigned ue = __float_as_uint(e) + 0x8000u;
    unsigned uo = __float_as_uint(o) + 0x8000u;
    return __builtin_amdgcn_perm(uo, ue, 0x07060302u);
}

// m -> (i0,i1): lexicographic pair from combinations(range(32),2).
__device__ __forceinline__ void pair_of_m(int m, int& i0, int& i1) {
    int a = 0, rem = m;
    while (rem >= (NC_ - 1 - a)) { rem -= (NC_ - 1 - a); ++a; }
    i0 = a; i1 = a + 1 + rem;
}

// ws layout (bytes)
#define OBUF_BYTES  ((size_t)M_ * B_ * 4)                  // 4,063,232
#define W2A_BYTES   ((size_t)M_ * 2 * 2 * 64 * 16)         // 2,031,616
#define NCHUNK 16
#define PBUF_BYTES  ((size_t)NCHUNK * B_ * CLS_ * 4)       // 1,310,720

// ---------------- one-time W2 -> bf16 MFMA-fragment prep ----------------
__global__ __launch_bounds__(256) void k_prep(
    const float* __restrict__ W2, int4* __restrict__ W2a)
{
    int t = blockIdx.x * 256 + threadIdx.x;      // 496*256 threads exactly
    int lane = t & 63, s = (t >> 6) & 1, u = (t >> 7) & 1, m = t >> 8;
    int q = lane >> 4, ln = lane & 15;
    const float* p = W2 + m * (H2_ * H1_) + (u * 16 + ln) * H1_ + s * 32 + q * 8;
    float4 f0 = *(const float4*)p;
    float4 f1 = *(const float4*)(p + 4);
    int4 d;
    d.x = ((unsigned)(unsigned short)f2bf(f0.x)) | ((unsigned)(unsigned short)f2bf(f0.y) << 16);
    d.y = ((unsigned)(unsigned short)f2bf(f0.z)) | ((unsigned)(unsigned short)f2bf(f0.w) << 16);
    d.z = ((unsigned)(unsigned short)f2bf(f1.x)) | ((unsigned)(unsigned short)f2bf(f1.y) << 16);
    d.w = ((unsigned)(unsigned short)f2bf(f1.z)) | ((unsigned)(unsigned short)f2bf(f1.w) << 16);
    W2a[t] = d;
}

// ---------------- main kernel ----------------
// grid = (M_, 4), block = 256 (4 waves). Wave w: 128 batches = 2 halves x 4 tiles x 16.
// MFMA roles: A = W2 [n x k], B = h1 [k x b]  ->  D[n][b].
template <bool PREP>
__global__ __launch_bounds__(256) void k_main3(
    const float* __restrict__ x,
    const float* __restrict__ W1, const float* __restrict__ b1,
    const float* __restrict__ g1, const float* __restrict__ be1,
    const float* __restrict__ m1, const float* __restrict__ v1,
    const float* __restrict__ W2, const int4* __restrict__ W2a,
    const float* __restrict__ b2p,
    const float* __restrict__ g2, const float* __restrict__ be2,
    const float* __restrict__ m2, const float* __restrict__ v2,
    const float* __restrict__ W3, const float* __restrict__ b3,
    float* __restrict__ obuf)
{
    __shared__ float w1aS[H1_], w1bS[H1_], c1S[H1_];
    __shared__ float s2S[H2_], c2S[H2_], w3S[H2_];
    __shared__ float xs0[512], xs1[512];

    const int m   = blockIdx.x;
    const int tid = threadIdx.x;

    int i0, i1;
    pair_of_m(m, i0, i1);

    if (tid < H1_) {                               // layer-1 BN fold
        int j = m * H1_ + tid;
        float s = g1[j] * rsqrtf(v1[j] + EPS_);
        w1aS[tid] = s * W1[2 * j];
        w1bS[tid] = s * W1[2 * j + 1];
        c1S[tid]  = fmaf(s, b1[j] - m1[j], be1[j]);
    } else if (tid < H1_ + H2_) {                  // layer-2 BN fold
        int o = tid - H1_;
        int j = m * H2_ + o;
        float s = g2[j] * rsqrtf(v2[j] + EPS_);
        s2S[o] = s;
        c2S[o] = fmaf(s, b2p[j] - m2[j], be2[j]);
        w3S[o] = W3[j];
    }
    {   // stage x columns for this block's 512 batches
        int bb = blockIdx.y * 512;
        xs0[tid]       = x[(bb + tid) * NC_ + i0];
        xs1[tid]       = x[(bb + tid) * NC_ + i1];
        xs0[256 + tid] = x[(bb + 256 + tid) * NC_ + i0];
        xs1[256 + tid] = x[(bb + 256 + tid) * NC_ + i1];
    }
    __syncthreads();

    const int lane = tid & 63;
    const int w    = tid >> 6;
    const int q    = lane >> 4;
    const int ln   = lane & 15;
    const int wbase = w * 128;                     // batch offset within block
    const float b3m = b3[m];

    // ---- W2 fragments (A operand): wfr[u][s] ----
    F8 wfr[2][2];
    if (PREP) {
        const int4* p = W2a + (m * 4) * 64 + lane;
#pragma unroll
        for (int u = 0; u < 2; ++u)
#pragma unroll
            for (int s = 0; s < 2; ++s)
                wfr[u][s].i = p[(u * 2 + s) * 64];
    } else {
        const float* W2m = W2 + m * (H2_ * H1_);
#pragma unroll
        for (int u = 0; u < 2; ++u)
#pragma unroll
            for (int s = 0; s < 2; ++s) {
                const float* p = W2m + (u * 16 + ln) * H1_ + s * 32 + q * 8;
                float4 f0 = *(const float4*)p;
                float4 f1 = *(const float4*)(p + 4);
                int4 d;
                d.x = ((unsigned)(unsigned short)f2bf(f0.x)) | ((unsigned)(unsigned short)f2bf(f0.y) << 16);
                d.y = ((unsigned)(unsigned short)f2bf(f0.z)) | ((unsigned)(unsigned short)f2bf(f0.w) << 16);
                d.z = ((unsigned)(unsigned short)f2bf(f1.x)) | ((unsigned)(unsigned short)f2bf(f1.y) << 16);
                d.w = ((unsigned)(unsigned short)f2bf(f1.z)) | ((unsigned)(unsigned short)f2bf(f1.w) << 16);
                wfr[u][s].i = d;
            }
    }

    // ---- epilogue constants (per-lane n-slots) ----
    float s2a0[4], c2a0[4], w3a0[4], s2a1[4], c2a1[4], w3a1[4];
#pragma unroll
    for (int r = 0; r < 4; ++r) {
        int n0 = q * 4 + r, n1 = 16 + n0;
        s2a0[r] = s2S[n0]; c2a0[r] = c2S[n0]; w3a0[r] = w3S[n0];
        s2a1[r] = s2S[n1]; c2a1[r] = c2S[n1]; w3a1[r] = w3S[n1];
    }

#pragma unroll
    for (int h = 0; h < 2; ++h) {
        const int hbase = wbase + h * 64;

        float x0v[4], x1v[4];
#pragma unroll
        for (int t = 0; t < 4; ++t) {
            x0v[t] = xs0[hbase + t * 16 + ln];
            x1v[t] = xs1[hbase + t * 16 + ln];
        }

        // ---- h1 fragments (B operand): k = s*32 + q*8 + j ----
        F8 hfr[4][2];
#pragma unroll
        for (int s = 0; s < 2; ++s)
#pragma unroll
            for (int jp = 0; jp < 4; ++jp) {
                int ke = s * 32 + q * 8 + 2 * jp;
                float wae = w1aS[ke],     wbe = w1bS[ke],     ce = c1S[ke];
                float wao = w1aS[ke + 1], wbo = w1bS[ke + 1], co = c1S[ke + 1];
                unsigned dw[4];
#pragma unroll
                for (int t = 0; t < 4; ++t) {
                    float he = fmaxf(fmaf(x0v[t], wae, fmaf(x1v[t], wbe, ce)), 0.f);
                    float ho = fmaxf(fmaf(x0v[t], wao, fmaf(x1v[t], wbo, co)), 0.f);
                    dw[t] = pack_bf2(he, ho);
                }
                hfr[0][s].i[jp] = dw[0];  hfr[1][s].i[jp] = dw[1];
                hfr[2][s].i[jp] = dw[2];  hfr[3][s].i[jp] = dw[3];
            }

        // ---- MFMA + epilogue ----
        float ot[4];
#pragma unroll
        for (int t = 0; t < 4; ++t) {
            f32x4 acc0 = {0.f, 0.f, 0.f, 0.f};
            f32x4 acc1 = {0.f, 0.f, 0.f, 0.f};
            acc0 = __builtin_amdgcn_mfma_f32_16x16x32_bf16(wfr[0][0].h, hfr[t][0].h, acc0, 0, 0, 0);
            acc0 = __builtin_amdgcn_mfma_f32_16x16x32_bf16(wfr[0][1].h, hfr[t][1].h, acc0, 0, 0, 0);
            acc1 = __builtin_amdgcn_mfma_f32_16x16x32_bf16(wfr[1][0].h, hfr[t][0].h, acc1, 0, 0, 0);
            acc1 = __builtin_amdgcn_mfma_f32_16x16x32_bf16(wfr[1][1].h, hfr[t][1].h, acc1, 0, 0, 0);

            float part = 0.f;
#pragma unroll
            for (int r = 0; r < 4; ++r) {
                float h20 = fmaxf(fmaf(s2a0[r], acc0[r], c2a0[r]), 0.f);
                float h21 = fmaxf(fmaf(s2a1[r], acc1[r], c2a1[r]), 0.f);
                part = fmaf(h20, w3a0[r], fmaf(h21, w3a1[r], part));
            }
            part += __shfl_xor(part, 16, 64);
            part += __shfl_xor(part, 32, 64);
            ot[t] = part;
        }

        // quad q stores tile t=q -> one coalesced 256B store per wave per half
        float o = (q == 0) ? ot[0] : (q == 1) ? ot[1] : (q == 2) ? ot[2] : ot[3];
        obuf[m * B_ + blockIdx.y * 512 + hbase + lane] = o + b3m;
    }
}

// ---------------- output projection, stage 1: partials ----------------
// grid = (32 b-tiles, 16 m-chunks of 31). block 256 = 64 b-lanes x 4 m-groups.
__global__ __launch_bounds__(256) void k_outp(
    const float* __restrict__ obuf, const float* __restrict__ Wout,
    float* __restrict__ pbuf)
{
    __shared__ float red[256 * CLS_];
    const int tid = threadIdx.x;
    const int bl  = tid & 63;
    const int mg  = tid >> 6;
    const int b   = blockIdx.x * 64 + bl;
    const int mb  = blockIdx.y * 31;

    float acc[CLS_];
#pragma unroll
    for (int c = 0; c < CLS_; ++c) acc[c] = 0.f;

    for (int i = mg; i < 31; i += 4) {
        int m = mb + i;
        float o = obuf[m * B_ + b];
#pragma unroll
        for (int c = 0; c < CLS_; ++c)
            acc[c] = fmaf(o, Wout[c * M_ + m], acc[c]);
    }
#pragma unroll
    for (int c = 0; c < CLS_; ++c) red[tid * CLS_ + c] = acc[c];
    __syncthreads();

    if (mg == 0) {
#pragma unroll
        for (int c = 0; c < CLS_; ++c) {
            float s = red[(0 * 64 + bl) * CLS_ + c] + red[(1 * 64 + bl) * CLS_ + c]
                    + red[(2 * 64 + bl) * CLS_ + c] + red[(3 * 64 + bl) * CLS_ + c];
            pbuf[(blockIdx.y * B_ + b) * CLS_ + c] = s;
        }
    }
}

// ---------------- output projection, stage 2: finish ----------------
__global__ __launch_bounds__(256) void k_fin(
    const float* __restrict__ pbuf, const float* __restrict__ bout,
    float* __restrict__ out)
{
    int t = blockIdx.x * 256 + threadIdx.x;       // B_*CLS_ = 20480 exactly
    int c = t % CLS_;
    float s = bout[c];
#pragma unroll
    for (int ch = 0; ch < NCHUNK; ++ch)
        s += pbuf[ch * (B_ * CLS_) + t];
    out[t] = s;
}

// ---------------- mid-tier single-stage k_out (obuf-only ws) ----------------
__global__ __launch_bounds__(256) void k_out1(
    const float* __restrict__ obuf, const float* __restrict__ Wout,
    const float* __restrict__ bout, float* __restrict__ out)
{
    __shared__ float red[256 * CLS_];
    const int tid = threadIdx.x;
    const int bl  = tid & 31;
    const int mg  = tid >> 5;
    const int b   = blockIdx.x * 32 + bl;

    float acc[CLS_];
#pragma unroll
    for (int c = 0; c < CLS_; ++c) acc[c] = 0.f;
#pragma unroll 4
    for (int m = mg; m < M_; m += 8) {
        float o = obuf[m * B_ + b];
#pragma unroll
        for (int c = 0; c < CLS_; ++c)
            acc[c] = fmaf(o, Wout[c * M_ + m], acc[c]);
    }
#pragma unroll
    for (int c = 0; c < CLS_; ++c) red[tid * CLS_ + c] = acc[c];
    __syncthreads();
    if (mg == 0) {
#pragma unroll
        for (int c = 0; c < CLS_; ++c) {
            float s = bout[c];
#pragma unroll
            for (int g = 0; g < 8; ++g)
                s += red[(g * 32 + bl) * CLS_ + c];
            out[b * CLS_ + c] = s;
        }
    }
}

// ---------------- workspace-free fallback (known-good) ----------------
__global__ __launch_bounds__(256) void k_fused(
    const float* __restrict__ x,
    const float* __restrict__ W1, const float* __restrict__ b1,
    const float* __restrict__ g1, const float* __restrict__ be1,
    const float* __restrict__ m1, const float* __restrict__ v1,
    const float* __restrict__ W2, const float* __restrict__ b2p,
    const float* __restrict__ g2, const float* __restrict__ be2,
    const float* __restrict__ m2, const float* __restrict__ v2,
    const float* __restrict__ W3, const float* __restrict__ b3,
    const float* __restrict__ Wout, const float* __restrict__ bout,
    float* __restrict__ out)
{
    __shared__ float red[256 * CLS_];
    const int tid = threadIdx.x;
    const int bl  = tid & 7;
    const int mg  = tid >> 3;
    const int b   = blockIdx.x * 8 + bl;

    float acc[CLS_];
#pragma unroll
    for (int c = 0; c < CLS_; ++c) acc[c] = 0.f;

    for (int m = mg; m < M_; m += 32) {
        int i0, i1;
        pair_of_m(m, i0, i1);
        const float x0 = x[b * NC_ + i0];
        const float x1 = x[b * NC_ + i1];
        float h1[H1_];
#pragma unroll
        for (int o = 0; o < H1_; ++o) {
            int j = m * H1_ + o;
            float s = g1[j] * rsqrtf(v1[j] + EPS_);
            float pre = fmaf(x0, s * W1[2 * j],
                        fmaf(x1, s * W1[2 * j + 1],
                             fmaf(s, b1[j] - m1[j], be1[j])));
            h1[o] = fmaxf(pre, 0.f);
        }
        float acc3 = b3[m];
#pragma unroll 2
        for (int o = 0; o < H2_; ++o) {
            int j = m * H2_ + o;
            const float* __restrict__ r = W2 + j * H1_;
            float d = 0.f;
#pragma unroll
            for (int i = 0; i < H1_; ++i) d = fmaf(h1[i], r[i], d);
            float s = g2[j] * rsqrtf(v2[j] + EPS_);
            float h2 = fmaxf(fmaf(s, d + b2p[j] - m2[j], be2[j]), 0.f);
            acc3 = fmaf(h2, W3[j], acc3);
        }
#pragma unroll
        for (int c = 0; c < CLS_; ++c)
            acc[c] = fmaf(acc3, Wout[c * M_ + m], acc[c]);
    }

#pragma unroll
    for (int c = 0; c < CLS_; ++c) red[tid * CLS_ + c] = acc[c];
    __syncthreads();
    if (mg == 0) {
#pragma unroll
        for (int c = 0; c < CLS_; ++c) {
            float s = bout[c];
            for (int g = 0; g < 32; ++g)
                s += red[(g * 8 + bl) * CLS_ + c];
            out[b * CLS_ + c] = s;
        }
    }
}

// ---------------- launch ----------------
extern "C" void kernel_launch(void* const* d_in, const int* in_sizes, int n_in,
                              void* d_out, int out_size, void* d_ws, size_t ws_size,
                              hipStream_t stream)
{
    const float* x    = (const float*)d_in[0];
    // d_in[1] (pair_idx) unused: recomputed on device (dtype-immune).
    const float* W1   = (const float*)d_in[2];
    const float* b1   = (const float*)d_in[3];
    const float* g1   = (const float*)d_in[4];
    const float* be1  = (const float*)d_in[5];
    const float* m1   = (const float*)d_in[6];
    const float* v1   = (const float*)d_in[7];
    const float* W2   = (const float*)d_in[8];
    const float* b2p  = (const float*)d_in[9];
    const float* g2   = (const float*)d_in[10];
    const float* be2  = (const float*)d_in[11];
    const float* m2   = (const float*)d_in[12];
    const float* v2   = (const float*)d_in[13];
    const float* W3   = (const float*)d_in[14];
    const float* b3   = (const float*)d_in[15];
    const float* Wout = (const float*)d_in[16];
    const float* bout = (const float*)d_in[17];
    float* out  = (float*)d_out;
    float* obuf = (float*)d_ws;
    int4*  W2a  = (int4*)((char*)d_ws + OBUF_BYTES);
    float* pbuf = (float*)((char*)d_ws + OBUF_BYTES + W2A_BYTES);

    if (ws_size >= OBUF_BYTES + W2A_BYTES + PBUF_BYTES) {
        k_prep<<<M_, 256, 0, stream>>>(W2, W2a);
        k_main3<true><<<dim3(M_, B_ / 512), 256, 0, stream>>>(
            x, W1, b1, g1, be1, m1, v1, W2, W2a,
            b2p, g2, be2, m2, v2, W3, b3, obuf);
        k_outp<<<dim3(B_ / 64, NCHUNK), 256, 0, stream>>>(obuf, Wout, pbuf);
        k_fin<<<(B_ * CLS_) / 256, 256, 0, stream>>>(pbuf, bout, out);
    } else if (ws_size >= OBUF_BYTES) {
        k_main3<false><<<dim3(M_, B_ / 512), 256, 0, stream>>>(
            x, W1, b1, g1, be1, m1, v1, W2, (const int4*)nullptr,
            b2p, g2, be2, m2, v2, W3, b3, obuf);
        k_out1<<<B_ / 32, 256, 0, stream>>>(obuf, Wout, bout, out);
    } else {
        k_fused<<<B_ / 8, 256, 0, stream>>>(
            x, W1, b1, g1, be1, m1, v1,
            W2, b2p, g2, be2, m2, v2, W3, b3, Wout, bout, out);
    }
}